// Round 10
// baseline (122.402 us; speedup 1.0000x reference)
//
#include <hip/hip_runtime.h>
#include <hip/hip_bf16.h>

#define B_   64
#define N_   256
#define P_   12
#define D_   128
#define BN_  (B_*N_)      // 16384
#define EPSV 1e-5f

typedef float  f32x4  __attribute__((ext_vector_type(4)));
typedef __bf16 bf16x8 __attribute__((ext_vector_type(8)));
typedef __bf16 bf16x4 __attribute__((ext_vector_type(4)));

// module-scope scratch (fully rewritten every launch -> deterministic)
__device__ float  g_avg[768*256];       // [b*12+p][n]  mean over d
__device__ float  g_mx [768*256];       // [b*12+p][n]  max over d
__device__ float  g_h1 [1536*128];      // rows 0..767 avg, 768..1535 max
__device__ float  g_pool[BN_*P_];       // [bn][p] = sig(avg)+sig(max)
__device__ float  g_y  [BN_*P_];        // [bn][p] = v . k   (from k1)
__device__ __bf16 g_v  [(size_t)BN_*8*64*4];      // v bf16, MFMA layout [bn][nt][l][r]
__device__ __align__(16) __bf16 g_wvbf[128*128];  // wv*sv, bf16, PRE-SWIZZLED
__device__ float  g_tv [128];           // BN shift

__device__ inline float sigm_(float x) { return 1.0f / (1.0f + __expf(-x)); }

__device__ inline float dot4_(float4 a, float4 b, float acc) {
  acc = fmaf(a.x, b.x, acc); acc = fmaf(a.y, b.y, acc);
  acc = fmaf(a.z, b.z, acc); acc = fmaf(a.w, b.w, acc);
  return acc;
}

// ---------------- K0: pre-bake wv -> scaled bf16, XOR-swizzled (R6-proven) --
__global__ __launch_bounds__(256) void k0_prep(const float* __restrict__ wv,
                                               const float* __restrict__ vg,
                                               const float* __restrict__ vb,
                                               const float* __restrict__ vrm,
                                               const float* __restrict__ vrv) {
  int t = blockIdx.x * 256 + threadIdx.x;   // 4096 threads, 4 bf16 each
  if (blockIdx.x == 0 && threadIdx.x < 128) {
    float s0 = vg[threadIdx.x] * rsqrtf(vrv[threadIdx.x] + EPSV);
    g_tv[threadIdx.x] = vb[threadIdx.x] - vrm[threadIdx.x] * s0;
  }
  int e = t >> 5;                 // 32 threads per 256B row
  float s = vg[e] * rsqrtf(vrv[e] + EPSV);
  int qbase = t * 8;              // output byte offset (8B per thread)
  int swz = (e & 7) << 4;
  bf16x4 h;
#pragma unroll
  for (int j = 0; j < 4; ++j) {
    int inner = ((qbase & 255) + j * 2) ^ swz;
    h[j] = (__bf16)(wv[e * 128 + (inner >> 1)] * s);
  }
  *(bf16x4*)((char*)g_wvbf + qbase) = h;
}

// ---------------- K1: pool stats + k-softmax + v via MFMA + y ---------------
// 2048 blocks x 256 thr; wave handles 2 bn. Phase A: coalesced x read, pool
// stats, k softmax (all BW-bound streaming). Phase B: A-frags from L1-hot x,
// B-frags from swizzled wv_lds (R4-R6 proven), 32 MFMA, silu epilogue ->
// v stored bf16 in MFMA layout (coalesced 8B stores) + y (v.k) reduced+stored.
// The MFMA/exp latency hides under phase A's streaming loads of other waves.
__global__ __launch_bounds__(256) void k1_pool(const float* __restrict__ x,
                                               const float* __restrict__ wk,
                                               const float* __restrict__ kg,
                                               const float* __restrict__ kb,
                                               const float* __restrict__ krm,
                                               const float* __restrict__ krv) {
  __shared__ __align__(16) __bf16 wv_lds[128 * 128];  // pre-swizzled, 32KB
  __shared__ float k_lds[4][128];

  int t = threadIdx.x, w = t >> 6, l = t & 63;
  {
    const uint4* src = (const uint4*)g_wvbf;
    uint4* dst = (uint4*)wv_lds;
#pragma unroll
    for (int i = 0; i < 8; ++i) dst[i * 256 + t] = src[i * 256 + t];
  }
  float ksc = kg[0] * rsqrtf(krv[0] + EPSV);
  float kbs = kb[0] - krm[0] * ksc;
  __syncthreads();   // wv_lds ready; read-only from here on

  int half = l >> 5, lane32 = l & 31;
  int bcol = l & 15;
  int arow = bcol > 11 ? 11 : bcol;          // clamp pad rows
  int ak = (l >> 4) * 8;
  int bko = (l >> 4) * 16;
  int p0 = (l >> 4) * 4;
  bool rows_ok = (p0 < 12);
  float tv_e[8];
#pragma unroll
  for (int nt = 0; nt < 8; ++nt) tv_e[nt] = g_tv[bcol + nt * 16];

  for (int it = 0; it < 2; ++it) {
    int bn = blockIdx.x * 8 + it * 4 + w;
    const float* xp = x + (size_t)bn * (P_ * D_);

    // ---- phase A: stats + k_raw over coalesced x rows ----
    float s6[6], m6[6];
    float kr0 = 0, kr1 = 0, kr2 = 0, kr3 = 0;
#pragma unroll
    for (int pp = 0; pp < 6; ++pp) {
      int p = pp * 2 + half;
      float4 v = *(const float4*)(xp + p * D_ + lane32 * 4);
      float wkp = wk[p];
      kr0 = fmaf(v.x, wkp, kr0); kr1 = fmaf(v.y, wkp, kr1);
      kr2 = fmaf(v.z, wkp, kr2); kr3 = fmaf(v.w, wkp, kr3);
      float s = (v.x + v.y) + (v.z + v.w);
      float m = fmaxf(fmaxf(v.x, v.y), fmaxf(v.z, v.w));
#pragma unroll
      for (int off = 16; off; off >>= 1) {
        s += __shfl_xor(s, off);
        m = fmaxf(m, __shfl_xor(m, off));
      }
      s6[pp] = s * (1.0f / D_);
      m6[pp] = m;
    }
    if (lane32 == 0) {
      int b = bn >> 8, n = bn & 255;
#pragma unroll
      for (int pp = 0; pp < 6; ++pp) {
        int p = pp * 2 + half;
        g_avg[(b * P_ + p) * N_ + n] = s6[pp];
        g_mx [(b * P_ + p) * N_ + n] = m6[pp];
      }
    }
    // k softmax (both halves hold full k_raw for e=lane32*4..+3 after xor-32)
    kr0 += __shfl_xor(kr0, 32); kr1 += __shfl_xor(kr1, 32);
    kr2 += __shfl_xor(kr2, 32); kr3 += __shfl_xor(kr3, 32);
    float z0 = kr0 * ksc + kbs, z1 = kr1 * ksc + kbs;
    float z2 = kr2 * ksc + kbs, z3 = kr3 * ksc + kbs;
    z0 = z0 * sigm_(z0); z1 = z1 * sigm_(z1);
    z2 = z2 * sigm_(z2); z3 = z3 * sigm_(z3);
    float mx = fmaxf(fmaxf(z0, z1), fmaxf(z2, z3));
#pragma unroll
    for (int off = 16; off; off >>= 1) mx = fmaxf(mx, __shfl_xor(mx, off));
    float e0 = __expf(z0 - mx), e1 = __expf(z1 - mx);
    float e2 = __expf(z2 - mx), e3 = __expf(z3 - mx);
    float es = (e0 + e1) + (e2 + e3);
#pragma unroll
    for (int off = 16; off; off >>= 1) es += __shfl_xor(es, off);
    float inv = 1.0f / es;
    if (half == 0) {
      float4 kk; kk.x = e0 * inv; kk.y = e1 * inv; kk.z = e2 * inv; kk.w = e3 * inv;
      *(float4*)(&k_lds[w][lane32 * 4]) = kk;
    }
    // same-wave LDS write->read (lgkmcnt ordering)
    float k_e[8];
#pragma unroll
    for (int nt = 0; nt < 8; ++nt) k_e[nt] = k_lds[w][bcol + nt * 16];

    // ---- phase B: A-frags (L1-hot x -> bf16), MFMA, silu, v+y stores ----
    bf16x8 afr[4];
#pragma unroll
    for (int ks = 0; ks < 4; ++ks) {
      const float* src = xp + arow * 128 + ks * 32 + ak;
      float4 lo = *(const float4*)(src);
      float4 hi = *(const float4*)(src + 4);
      bf16x8 a;
      a[0] = (__bf16)lo.x; a[1] = (__bf16)lo.y; a[2] = (__bf16)lo.z; a[3] = (__bf16)lo.w;
      a[4] = (__bf16)hi.x; a[5] = (__bf16)hi.y; a[6] = (__bf16)hi.z; a[7] = (__bf16)hi.w;
      afr[ks] = a;
    }
    float y_r[4] = {0.f, 0.f, 0.f, 0.f};
    __bf16* vp = g_v + ((size_t)bn * 8) * 256 + l * 4;
#pragma unroll
    for (int nt = 0; nt < 8; ++nt) {
      int er = bcol + nt * 16;
      int base = er * 256;
      int sw = (er & 7) << 4;
      f32x4 acc = (f32x4){0.f, 0.f, 0.f, 0.f};
#pragma unroll
      for (int ks = 0; ks < 4; ++ks) {
        int byte = (base + ks * 64 + bko) ^ sw;
        bf16x8 bfr = *(const bf16x8*)((const char*)wv_lds + byte);
        acc = __builtin_amdgcn_mfma_f32_16x16x32_bf16(afr[ks], bfr, acc, 0, 0, 0);
      }
      float tvv = tv_e[nt];
      bf16x4 vb;
#pragma unroll
      for (int r = 0; r < 4; ++r) {
        float a = acc[r] + tvv;
        float v = a * sigm_(a);
        y_r[r] = fmaf(v, k_e[nt], y_r[r]);
        vb[r] = (__bf16)v;
      }
      // all 4 r-groups written (clamped rows -> finite): no poison downstream
      *(bf16x4*)(vp + nt * 256) = vb;
    }
    // y[p]: reduce over the 16 lanes of the column group, store by col-0 lanes
#pragma unroll
    for (int r = 0; r < 4; ++r) {
#pragma unroll
      for (int off = 8; off; off >>= 1) y_r[r] += __shfl_xor(y_r[r], off);
    }
    if (bcol == 0 && rows_ok) {
      float4 yq; yq.x = y_r[0]; yq.y = y_r[1]; yq.z = y_r[2]; yq.w = y_r[3];
      *(float4*)(g_y + (size_t)bn * 12 + p0) = yq;
    }
  }
}

// ---------------- K2a: layer1 (256->128) + exact GELU -----------------------
__global__ __launch_bounds__(256) void k2_l1(const float* __restrict__ w_avg1,
                                             const float* __restrict__ w_max1) {
  __shared__ float in_t[16 * 256];
  __shared__ float w_t[64 * 68];
  int t = threadIdx.x;
  int rblk = blockIdx.x % 96, cblk = blockIdx.x / 96;
  int rr0 = rblk * 16, c0 = cblk * 64;
  bool mxb = (rr0 >= 768);
  int r768 = mxb ? rr0 - 768 : rr0;
  const float* in = (mxb ? g_mx : g_avg) + (size_t)r768 * 256;
  const float* w1 = mxb ? w_max1 : w_avg1;
#pragma unroll
  for (int i = 0; i < 4; ++i) {
    int F = t + i * 256, r = F >> 6, k4 = F & 63;
    *(float4*)(in_t + r * 256 + k4 * 4) = *(const float4*)(in + r * 256 + k4 * 4);
  }
  int c = t & 63, rq = t >> 6;
  float a0 = 0, a1 = 0, a2 = 0, a3 = 0;
  for (int kc = 0; kc < 4; ++kc) {
    __syncthreads();
#pragma unroll
    for (int i = 0; i < 4; ++i) {
      int F = t + i * 256, cr = F >> 4, k4 = F & 15;
      *(float4*)(w_t + cr * 68 + k4 * 4) =
          *(const float4*)(w1 + (size_t)(c0 + cr) * 256 + kc * 64 + k4 * 4);
    }
    __syncthreads();
#pragma unroll
    for (int k4 = 0; k4 < 16; ++k4) {
      float4 wv4 = *(float4*)(w_t + c * 68 + k4 * 4);
      a0 = dot4_(*(float4*)(in_t + (rq * 4 + 0) * 256 + kc * 64 + k4 * 4), wv4, a0);
      a1 = dot4_(*(float4*)(in_t + (rq * 4 + 1) * 256 + kc * 64 + k4 * 4), wv4, a1);
      a2 = dot4_(*(float4*)(in_t + (rq * 4 + 2) * 256 + kc * 64 + k4 * 4), wv4, a2);
      a3 = dot4_(*(float4*)(in_t + (rq * 4 + 3) * 256 + kc * 64 + k4 * 4), wv4, a3);
    }
  }
  float accs[4] = {a0, a1, a2, a3};
#pragma unroll
  for (int r = 0; r < 4; ++r) {
    float a = accs[r];
    float g = 0.5f * a * (1.0f + erff(a * 0.70710678f));
    g_h1[(size_t)(rr0 + rq * 4 + r) * 128 + c0 + c] = g;
  }
}

// ---------------- K2b: layer2 (128->256), sigmoid, branch-sum ---------------
__global__ __launch_bounds__(256) void k2_l2(const float* __restrict__ w_avg2,
                                             const float* __restrict__ w_max2) {
  __shared__ float ina_t[16 * 128];
  __shared__ float inm_t[16 * 128];
  __shared__ float wa_t[64 * 68];
  __shared__ float wm_t[64 * 68];
  int t = threadIdx.x;
  int rblk = blockIdx.x % 48, cblk = blockIdx.x / 48;
  int rr0 = rblk * 16, n0 = cblk * 64;
#pragma unroll
  for (int i = 0; i < 2; ++i) {
    int F = t + i * 256, r = F >> 5, k4 = F & 31;
    *(float4*)(ina_t + r * 128 + k4 * 4) = *(const float4*)(g_h1 + (size_t)(rr0 + r) * 128 + k4 * 4);
    *(float4*)(inm_t + r * 128 + k4 * 4) = *(const float4*)(g_h1 + (size_t)(768 + rr0 + r) * 128 + k4 * 4);
  }
  int c = t & 63, rq = t >> 6;
  float aa0=0, aa1=0, aa2=0, aa3=0, am0=0, am1=0, am2=0, am3=0;
  for (int kc = 0; kc < 2; ++kc) {
    __syncthreads();
#pragma unroll
    for (int i = 0; i < 4; ++i) {
      int F = t + i * 256, cr = F >> 4, k4 = F & 15;
      *(float4*)(wa_t + cr * 68 + k4 * 4) =
          *(const float4*)(w_avg2 + (size_t)(n0 + cr) * 128 + kc * 64 + k4 * 4);
      *(float4*)(wm_t + cr * 68 + k4 * 4) =
          *(const float4*)(w_max2 + (size_t)(n0 + cr) * 128 + kc * 64 + k4 * 4);
    }
    __syncthreads();
#pragma unroll
    for (int k4 = 0; k4 < 16; ++k4) {
      float4 wa4 = *(float4*)(wa_t + c * 68 + k4 * 4);
      float4 wm4 = *(float4*)(wm_t + c * 68 + k4 * 4);
      float4 i0 = *(float4*)(ina_t + (rq * 4 + 0) * 128 + kc * 64 + k4 * 4);
      float4 i1 = *(float4*)(ina_t + (rq * 4 + 1) * 128 + kc * 64 + k4 * 4);
      float4 i2 = *(float4*)(ina_t + (rq * 4 + 2) * 128 + kc * 64 + k4 * 4);
      float4 i3 = *(float4*)(ina_t + (rq * 4 + 3) * 128 + kc * 64 + k4 * 4);
      aa0 = dot4_(i0, wa4, aa0); aa1 = dot4_(i1, wa4, aa1);
      aa2 = dot4_(i2, wa4, aa2); aa3 = dot4_(i3, wa4, aa3);
      float4 j0 = *(float4*)(inm_t + (rq * 4 + 0) * 128 + kc * 64 + k4 * 4);
      float4 j1 = *(float4*)(inm_t + (rq * 4 + 1) * 128 + kc * 64 + k4 * 4);
      float4 j2 = *(float4*)(inm_t + (rq * 4 + 2) * 128 + kc * 64 + k4 * 4);
      float4 j3 = *(float4*)(inm_t + (rq * 4 + 3) * 128 + kc * 64 + k4 * 4);
      am0 = dot4_(j0, wm4, am0); am1 = dot4_(j1, wm4, am1);
      am2 = dot4_(j2, wm4, am2); am3 = dot4_(j3, wm4, am3);
    }
  }
  float va[4] = {aa0, aa1, aa2, aa3};
  float vm[4] = {am0, am1, am2, am3};
#pragma unroll
  for (int r = 0; r < 4; ++r) {
    int rr = rr0 + rq * 4 + r;
    int b = rr / 12, p = rr % 12;
    float pv = sigm_(va[r]) + sigm_(vm[r]);
    g_pool[((size_t)b * 256 + (n0 + c)) * 12 + p] = pv;
  }
}

// ---------------- K3: streaming finale — y_pool gate + outer product --------
// 16384 blocks x 64 thr, one bn per wave. No MFMA, no exp, no LDS: read v
// (bf16, MFMA layout, coalesced), 32 FMA -> y_pool partials, proven shfl
// reduce/gather (R9), y[p] from g_y (wave-uniform scalar loads), coalesced
// float2 row stores. Low VGPR -> high occupancy; near store-BW-bound.
__global__ __launch_bounds__(64) void k3_main(float* __restrict__ out) {
  int l = threadIdx.x;
  int bn = blockIdx.x;
  int p0 = (l >> 4) * 4;
  bool rows_ok = (p0 < 12);

  float pool_r[4] = {0.f, 0.f, 0.f, 0.f};
  if (rows_ok) {
    const float* pp = g_pool + (size_t)bn * 12 + p0;
#pragma unroll
    for (int r = 0; r < 4; ++r) pool_r[r] = pp[r];
  }

  // ypp[nt] = sum_r pool[p0+r] * v[p0+r][bcol+nt*16]
  const __bf16* vp = g_v + ((size_t)bn * 8) * 256 + l * 4;
  float ypp[8];
#pragma unroll
  for (int nt = 0; nt < 8; ++nt) {
    bf16x4 vb = *(const bf16x4*)(vp + nt * 256);
    float s = 0.f;
#pragma unroll
    for (int r = 0; r < 4; ++r) s = fmaf(pool_r[r], (float)vb[r], s);
    ypp[nt] = s;
  }
  // reduce across the 4 row groups
#pragma unroll
  for (int nt = 0; nt < 8; ++nt) {
    ypp[nt] += __shfl_xor(ypp[nt], 16);
    ypp[nt] += __shfl_xor(ypp[nt], 32);
  }
  // gather this lane's two output columns e=2l,2l+1 (R9-proven pattern)
  int cs = (l & 7) * 2;
  int ntw = l >> 3;
  float ypx = 0.f, ypy = 0.f;
#pragma unroll
  for (int nt = 0; nt < 8; ++nt) {
    float sx = __shfl(ypp[nt], cs);
    float sy = __shfl(ypp[nt], cs + 1);
    ypx = (ntw == nt) ? sx : ypx;
    ypy = (ntw == nt) ? sy : ypy;
  }

  // out[p][e] = y[p] * y_pool[e], coalesced float2 row stores
  const float* yb = g_y + (size_t)bn * 12;
  float* op = out + (size_t)bn * (P_ * D_);
#pragma unroll
  for (int p = 0; p < P_; ++p) {
    float yp = yb[p];            // wave-uniform -> scalar load
    float2 o;
    o.x = yp * ypx;
    o.y = yp * ypy;
    *(float2*)(op + p * 128 + 2 * l) = o;
  }
}

extern "C" void kernel_launch(void* const* d_in, const int* in_sizes, int n_in,
                              void* d_out, int out_size, void* d_ws, size_t ws_size,
                              hipStream_t stream) {
  const float* x   = (const float*)d_in[0];
  const float* wk  = (const float*)d_in[1];
  const float* kg  = (const float*)d_in[2];
  const float* kbb = (const float*)d_in[3];
  const float* krm = (const float*)d_in[4];
  const float* krv = (const float*)d_in[5];
  const float* wvp = (const float*)d_in[6];
  const float* vg  = (const float*)d_in[7];
  const float* vbb = (const float*)d_in[8];
  const float* vrm = (const float*)d_in[9];
  const float* vrv = (const float*)d_in[10];
  const float* wa1 = (const float*)d_in[11];
  const float* wa2 = (const float*)d_in[12];
  const float* wm1 = (const float*)d_in[13];
  const float* wm2 = (const float*)d_in[14];
  float* out = (float*)d_out;

  k0_prep<<<16, 256, 0, stream>>>(wvp, vg, vbb, vrm, vrv);
  k1_pool<<<2048, 256, 0, stream>>>(x, wk, kg, kbb, krm, krv);
  k2_l1<<<192, 256, 0, stream>>>(wa1, wm1);
  k2_l2<<<192, 256, 0, stream>>>(wa2, wm2);
  k3_main<<<16384, 64, 0, stream>>>(out);
}